// Round 1
// baseline (590.612 us; speedup 1.0000x reference)
//
#include <hip/hip_runtime.h>
#include <math.h>

#define PADR 264  // padded row stride (floats) for LDS tiles: breaks 32-bank alignment

// ---------------------------------------------------------------------------
// K2: q = queries@Wq + bq (kept in LDS);
//     R[s,h,d] = scale * sum_c q[s,h*32+c] * Wkv[d*512 + h*32+c]   (k-part)
//     c0[s,h]  = scale * sum_c q[s,h*32+c] * bkv[h*32+c]
// 16 samples per block to amortize weight reads through L2.
// ---------------------------------------------------------------------------
__global__ __launch_bounds__(256) void k2_qr(
    const float* __restrict__ queries, const float* __restrict__ Wq,
    const float* __restrict__ bq, const float* __restrict__ Wkv,
    const float* __restrict__ bkv, float* __restrict__ Rws,
    float* __restrict__ c0ws) {
  __shared__ float sQin[16][256];
  __shared__ float sQ[16][256];
  const int t = threadIdx.x;
  const int s0 = blockIdx.x * 16;
  #pragma unroll 4
  for (int r = 0; r < 16; ++r) sQin[r][t] = queries[(size_t)(s0 + r) * 256 + t];
  __syncthreads();
  float acc[16];
  const float bqt = bq[t];
  #pragma unroll
  for (int r = 0; r < 16; ++r) acc[r] = bqt;
  for (int d = 0; d < 256; ++d) {
    const float wv = Wq[d * 256 + t];
    #pragma unroll
    for (int r = 0; r < 16; ++r) acc[r] += sQin[r][d] * wv;
  }
  #pragma unroll
  for (int r = 0; r < 16; ++r) sQ[r][t] = acc[r];
  __syncthreads();

  const int h = t >> 5, dl = t & 31;
  const float scale = 0.1767766952966369f;  // 1/sqrt(32)
  for (int k = 0; k < 8; ++k) {
    const int d = dl + 32 * k;
    float wk[32];
    #pragma unroll
    for (int c4 = 0; c4 < 8; ++c4) {
      const float4 v = *(const float4*)&Wkv[d * 512 + h * 32 + c4 * 4];
      wk[c4 * 4 + 0] = v.x; wk[c4 * 4 + 1] = v.y;
      wk[c4 * 4 + 2] = v.z; wk[c4 * 4 + 3] = v.w;
    }
    for (int r = 0; r < 16; ++r) {
      float a = 0.f;
      #pragma unroll
      for (int c = 0; c < 32; ++c) a += sQ[r][h * 32 + c] * wk[c];
      Rws[(size_t)(s0 + r) * 2048 + h * 256 + d] = a * scale;
    }
  }
  if (t < 128) {
    const int sl = t >> 3, hh = t & 7;
    float a = 0.f;
    #pragma unroll
    for (int c = 0; c < 32; ++c) a += sQ[sl][hh * 32 + c] * bkv[hh * 32 + c];
    c0ws[(s0 + sl) * 8 + hh] = a * scale;
  }
}

// ---------------------------------------------------------------------------
// K3: one block per sample. 4 waves; each wave processes batches of 8 elements.
// lane = e*8 + h (e = element-in-batch, h = head): each lane computes the FULL
// 256-d score dot for its (elem,head) -> no cross-lane reduction for scores.
// Online softmax per wave (m, denom, A[h][d-window]); flash-combine across
// waves at the end; writes A_f[s,h,d] = sum_n probs[n,h]*E[n,d].
// LDS sEA is a union: E staging during main loop, per-wave A for the combine.
// ---------------------------------------------------------------------------
__global__ __launch_bounds__(256) void k3_attn(
    const float* __restrict__ E, const int* __restrict__ idx,
    const float* __restrict__ Rws, const float* __restrict__ c0ws,
    float* __restrict__ AFws, int N) {
  __shared__ float sEA[4][8][PADR];   // 33.8 KB (E staging, then per-wave A)
  __shared__ float sR[8][PADR];       // 8.4 KB
  __shared__ float sMD[2][4][8];
  __shared__ float sSc[4][8];
  __shared__ float sC0[8];
  __shared__ int sRange[2];
  const int s = blockIdx.x;
  const int t = threadIdx.x;
  const int w = t >> 6, lane = t & 63;
  const int e = lane >> 3, h = lane & 7;

  if (t == 0) {
    int lo = 0, hi = N;
    while (lo < hi) { int mid = (lo + hi) >> 1; if (idx[mid] < s) lo = mid + 1; else hi = mid; }
    sRange[0] = lo;
    int lo2 = lo, hi2 = N;
    while (lo2 < hi2) { int mid = (lo2 + hi2) >> 1; if (idx[mid] < s + 1) lo2 = mid + 1; else hi2 = mid; }
    sRange[1] = lo2;
  }
  #pragma unroll
  for (int i = 0; i < 8; ++i) {
    const int id = t + 256 * i;
    sR[id >> 8][id & 255] = Rws[(size_t)s * 2048 + id];
  }
  if (t < 8) sC0[t] = c0ws[s * 8 + t];
  __syncthreads();
  const int start = sRange[0], end = sRange[1];

  float4 A[8];
  #pragma unroll
  for (int k = 0; k < 8; ++k) A[k] = make_float4(0.f, 0.f, 0.f, 0.f);
  float m = -INFINITY, dsum = 0.f;
  const float c0h = sC0[h];

  for (int n0 = start + w * 8; n0 < end; n0 += 32) {
    // stage 8 E rows (zero-fill out-of-range rows)
    #pragma unroll
    for (int r = 0; r < 8; ++r) {
      const int n = n0 + r;
      float4 ev = make_float4(0.f, 0.f, 0.f, 0.f);
      if (n < end) ev = *(const float4*)&E[(size_t)n * 256 + (lane << 2)];
      *(float4*)&sEA[w][r][lane << 2] = ev;
    }
    // full score dot for (e, h)
    float sc = c0h;
    #pragma unroll 8
    for (int d4 = 0; d4 < 64; ++d4) {
      const float4 ev = *(const float4*)&sEA[w][e][d4 * 4];
      const float4 rv = *(const float4*)&sR[h][d4 * 4];
      sc += ev.x * rv.x + ev.y * rv.y + ev.z * rv.z + ev.w * rv.w;
    }
    if (n0 + e >= end) sc = -INFINITY;
    // batch max over the 8 e-lanes of this head (lane bits 3..5)
    float tm = sc;
    tm = fmaxf(tm, __shfl_xor(tm, 8));
    tm = fmaxf(tm, __shfl_xor(tm, 16));
    tm = fmaxf(tm, __shfl_xor(tm, 32));
    const float mn = fmaxf(m, tm);
    const float corr = __expf(m - mn);       // m=-inf -> 0
    const float p = __expf(sc - mn);         // sc=-inf -> 0
    float ps = p;
    ps += __shfl_xor(ps, 8); ps += __shfl_xor(ps, 16); ps += __shfl_xor(ps, 32);
    dsum = dsum * corr + ps;
    m = mn;
    float pa[8];
    #pragma unroll
    for (int ee = 0; ee < 8; ++ee) pa[ee] = __shfl(p, (ee << 3) | h);
    // A[h][k*32 + e*4 .. +3] update; e*4 stagger keeps b128 reads conflict-light
    #pragma unroll
    for (int k = 0; k < 8; ++k) {
      float4 a = A[k];
      a.x *= corr; a.y *= corr; a.z *= corr; a.w *= corr;
      #pragma unroll
      for (int ee = 0; ee < 8; ++ee) {
        const float4 ev = *(const float4*)&sEA[w][ee][k * 32 + (e << 2)];
        a.x += pa[ee] * ev.x; a.y += pa[ee] * ev.y;
        a.z += pa[ee] * ev.z; a.w += pa[ee] * ev.w;
      }
      A[k] = a;
    }
  }
  __syncthreads();  // everyone done using sEA as E staging
  #pragma unroll
  for (int k = 0; k < 8; ++k) *(float4*)&sEA[w][h][k * 32 + (e << 2)] = A[k];
  if (lane < 8) { sMD[0][w][lane] = m; sMD[1][w][lane] = dsum; }
  __syncthreads();
  if (t < 8) {
    float M = -INFINITY;
    #pragma unroll
    for (int ww = 0; ww < 4; ++ww) M = fmaxf(M, sMD[0][ww][t]);
    float den = 0.f, scw[4];
    #pragma unroll
    for (int ww = 0; ww < 4; ++ww) {
      const float mw = sMD[0][ww][t];
      const float sv = (mw == -INFINITY) ? 0.f : __expf(mw - M);
      scw[ww] = sv;
      den += sMD[1][ww][t] * sv;
    }
    const float dinv = (den > 0.f) ? 1.f / den : 0.f;
    #pragma unroll
    for (int ww = 0; ww < 4; ++ww) sSc[ww][t] = scw[ww] * dinv;
  }
  __syncthreads();
  #pragma unroll
  for (int i = 0; i < 8; ++i) {
    const int id = t + 256 * i;
    const int hh = id >> 8, dd = id & 255;
    const float v = sEA[0][hh][dd] * sSc[0][hh] + sEA[1][hh][dd] * sSc[1][hh]
                  + sEA[2][hh][dd] * sSc[2][hh] + sEA[3][hh][dd] * sSc[3][hh];
    AFws[(size_t)s * 2048 + id] = v;
  }
}

// ---------------------------------------------------------------------------
// K4: pooled[s, h*32+c] = sum_d A_f[s,h,d] * Wv[d, h*32+c] + bv[h*32+c]
// block = (head h, 64 samples); Wv_h staged in LDS (32 KB).
// ---------------------------------------------------------------------------
__global__ __launch_bounds__(256) void k4_pooled(
    const float* __restrict__ AFws, const float* __restrict__ Wkv,
    const float* __restrict__ bkv, float* __restrict__ pooled) {
  __shared__ float sWv[256][32];
  const int t = threadIdx.x;
  const int h = blockIdx.x & 7, sg = blockIdx.x >> 3;
  const int s0 = sg * 64;
  #pragma unroll 8
  for (int i = 0; i < 32; ++i) {
    const int id = t + 256 * i;
    sWv[id >> 5][id & 31] = Wkv[(id >> 5) * 512 + 256 + h * 32 + (id & 31)];
  }
  __syncthreads();
  const int c = t & 31, sl = t >> 5;
  const float bv = bkv[256 + h * 32 + c];
  for (int ss = 0; ss < 8; ++ss) {
    const int s = s0 + sl * 8 + ss;
    const float* af = &AFws[(size_t)s * 2048 + h * 256];
    float a = bv;
    #pragma unroll 8
    for (int d4 = 0; d4 < 64; ++d4) {
      const float4 v = *(const float4*)&af[d4 * 4];
      a += v.x * sWv[d4 * 4 + 0][c] + v.y * sWv[d4 * 4 + 1][c]
         + v.z * sWv[d4 * 4 + 2][c] + v.w * sWv[d4 * 4 + 3][c];
    }
    pooled[(size_t)s * 256 + h * 32 + c] = a;
  }
}

// ---------------------------------------------------------------------------
// K5: out = pooled @ Wo + bo, 16 samples per block.
// ---------------------------------------------------------------------------
__global__ __launch_bounds__(256) void k5_out(
    const float* __restrict__ pooled, const float* __restrict__ Wo,
    const float* __restrict__ bo, float* __restrict__ out) {
  __shared__ float sP[16][256];
  const int t = threadIdx.x;
  const int s0 = blockIdx.x * 16;
  #pragma unroll 4
  for (int r = 0; r < 16; ++r) sP[r][t] = pooled[(size_t)(s0 + r) * 256 + t];
  __syncthreads();
  float acc[16];
  const float bot = bo[t];
  #pragma unroll
  for (int r = 0; r < 16; ++r) acc[r] = bot;
  for (int j = 0; j < 256; ++j) {
    const float wv = Wo[j * 256 + t];
    #pragma unroll
    for (int r = 0; r < 16; ++r) acc[r] += sP[r][j] * wv;
  }
  #pragma unroll
  for (int r = 0; r < 16; ++r) out[(size_t)(s0 + r) * 256 + t] = acc[r];
}

extern "C" void kernel_launch(void* const* d_in, const int* in_sizes, int n_in,
                              void* d_out, int out_size, void* d_ws, size_t ws_size,
                              hipStream_t stream) {
  const float* queries = (const float*)d_in[0];
  const float* E       = (const float*)d_in[1];
  const int*   idx     = (const int*)d_in[2];
  // d_in[3] = num_samples (unused; derived from sizes)
  const float* Wq  = (const float*)d_in[4];
  const float* bq  = (const float*)d_in[5];
  const float* Wkv = (const float*)d_in[6];
  const float* bkv = (const float*)d_in[7];
  const float* Wo  = (const float*)d_in[8];
  const float* bo  = (const float*)d_in[9];
  float* out = (float*)d_out;
  const int S = in_sizes[0] / 256;   // 4096
  const int N = in_sizes[1] / 256;   // 262144

  // workspace layout (floats): R[S*2048] | c0[S*8] | A_f[S*2048] | pooled[S*256]
  float* ws    = (float*)d_ws;
  float* Rws   = ws;
  float* c0ws  = Rws + (size_t)S * 2048;
  float* AFws  = c0ws + (size_t)S * 8;
  float* pld   = AFws + (size_t)S * 2048;
  // total = S*4360*4 bytes ~= 71.4 MB

  k2_qr   <<<S / 16,        256, 0, stream>>>(queries, Wq, bq, Wkv, bkv, Rws, c0ws);
  k3_attn <<<S,             256, 0, stream>>>(E, idx, Rws, c0ws, AFws, N);
  k4_pooled<<<(S / 64) * 8, 256, 0, stream>>>(AFws, Wkv, bkv, pld);
  k5_out  <<<S / 16,        256, 0, stream>>>(pld, Wo, bo, out);
}

// Round 2
// 552.828 us; speedup vs baseline: 1.0683x; 1.0683x over previous
//
#include <hip/hip_runtime.h>
#include <math.h>

// ---------------------------------------------------------------------------
// K0: offs[s] = first n with idx[n] >= s  (idx sorted). offs[S] = N.
// ---------------------------------------------------------------------------
__global__ __launch_bounds__(256) void k0_offsets(
    const int* __restrict__ idx, int* __restrict__ offs, int N, int S) {
  const int n = blockIdx.x * 256 + threadIdx.x;
  if (n >= N) return;
  const int cur = idx[n];
  const int prev = (n == 0) ? -1 : idx[n - 1];
  for (int s2 = prev + 1; s2 <= cur; ++s2) offs[s2] = n;
  if (n == N - 1) {
    for (int s2 = cur + 1; s2 <= S; ++s2) offs[s2] = N;
  }
}

// ---------------------------------------------------------------------------
// K2a: q = queries @ Wq + bq.  16 samples/block, thread owns output col t.
// ---------------------------------------------------------------------------
__global__ __launch_bounds__(256) void k2a_q(
    const float* __restrict__ queries, const float* __restrict__ Wq,
    const float* __restrict__ bq, float* __restrict__ qws) {
  __shared__ float sQ[16][256];
  const int t = threadIdx.x;
  const int s0 = blockIdx.x * 16;
  #pragma unroll 4
  for (int r = 0; r < 16; ++r) sQ[r][t] = queries[(size_t)(s0 + r) * 256 + t];
  __syncthreads();
  float acc[16];
  const float bqt = bq[t];
  #pragma unroll
  for (int r = 0; r < 16; ++r) acc[r] = bqt;
  for (int d4 = 0; d4 < 64; ++d4) {
    const float w0 = Wq[(d4 * 4 + 0) * 256 + t];
    const float w1 = Wq[(d4 * 4 + 1) * 256 + t];
    const float w2 = Wq[(d4 * 4 + 2) * 256 + t];
    const float w3 = Wq[(d4 * 4 + 3) * 256 + t];
    #pragma unroll
    for (int r = 0; r < 16; ++r) {
      const float4 qv = *(const float4*)&sQ[r][d4 * 4];
      acc[r] += qv.x * w0 + qv.y * w1 + qv.z * w2 + qv.w * w3;
    }
  }
  #pragma unroll
  for (int r = 0; r < 16; ++r) qws[(size_t)(s0 + r) * 256 + t] = acc[r];
}

// ---------------------------------------------------------------------------
// K2b: R[s,h,d] = scale * sum_c q[s,h*32+c] * Wkv[d*512 + h*32+c]
//      c0[s,h]  = scale * sum_c q[s,h*32+c] * bkv[h*32+c]
// block = (16 samples, head h). Wk_h staged TRANSPOSED in LDS (coalesced
// loads, padded rows); thread owns output d = t.
// ---------------------------------------------------------------------------
__global__ __launch_bounds__(256) void k2b_r(
    const float* __restrict__ qws, const float* __restrict__ Wkv,
    const float* __restrict__ bkv, float* __restrict__ Rws,
    float* __restrict__ c0ws) {
  __shared__ float sWk[32][257];  // [c][d]
  __shared__ float sq[16][32];    // [s][c]
  const int t = threadIdx.x;
  const int h = blockIdx.x & 7, sg = blockIdx.x >> 3;
  const int s0 = sg * 16;
  #pragma unroll 8
  for (int i = 0; i < 32; ++i) {
    const int id = t + 256 * i;
    sWk[id & 31][id >> 5] = Wkv[(id >> 5) * 512 + h * 32 + (id & 31)];
  }
  #pragma unroll
  for (int i = 0; i < 2; ++i) {
    const int id = t + 256 * i;
    sq[id >> 5][id & 31] = qws[(size_t)(s0 + (id >> 5)) * 256 + h * 32 + (id & 31)];
  }
  __syncthreads();
  const float scale = 0.1767766952966369f;  // 1/sqrt(32)
  float wk[32];
  #pragma unroll
  for (int c = 0; c < 32; ++c) wk[c] = sWk[c][t];
  for (int s = 0; s < 16; ++s) {
    float a = 0.f;
    #pragma unroll
    for (int c4 = 0; c4 < 8; ++c4) {
      const float4 qv = *(const float4*)&sq[s][c4 * 4];
      a += qv.x * wk[c4 * 4 + 0] + qv.y * wk[c4 * 4 + 1]
         + qv.z * wk[c4 * 4 + 2] + qv.w * wk[c4 * 4 + 3];
    }
    Rws[(size_t)(s0 + s) * 2048 + h * 256 + t] = a * scale;
  }
  if (t < 16) {
    float a = 0.f;
    #pragma unroll
    for (int c = 0; c < 32; ++c) a += sq[t][c] * bkv[h * 32 + c];
    c0ws[(s0 + t) * 8 + h] = a * scale;
  }
}

// ---------------------------------------------------------------------------
// K3: one WAVE per sample (4 samples/block, no barriers, no cross-wave work).
// lane = (dc = lane>>3, h = lane&7): R[h][dc*32..+31] in 32 VGPRs; per batch
// of 8 E-rows: slice-partial score dots + 3-shfl dc-reduce, then fully
// register-local online softmax; A[h][dc-slice] accumulated in 32 VGPRs.
// E rows staged slice-transposed in LDS (elem c of slice dc at j*32+dc*4):
// all score/A reads are bank-conflict-free with uniform reg indices.
// ---------------------------------------------------------------------------
__global__ __launch_bounds__(256) void k3_attn(
    const float* __restrict__ E, const int* __restrict__ offs,
    const float* __restrict__ Rws, const float* __restrict__ c0ws,
    float* __restrict__ AFws) {
  __shared__ float sE[4][8][256];  // 32 KB, per-wave private
  const int t = threadIdx.x;
  const int w = t >> 6, lane = t & 63;
  const int h = lane & 7, dc = lane >> 3;
  const int s = blockIdx.x * 4 + w;
  const int start = offs[s], end = offs[s + 1];

  float4 rv[8];
  const float* rp = &Rws[(size_t)s * 2048 + h * 256 + dc * 32];
  #pragma unroll
  for (int j = 0; j < 8; ++j) rv[j] = *(const float4*)(rp + j * 4);
  const float c0h = c0ws[s * 8 + h];

  float4 A[8];
  #pragma unroll
  for (int j = 0; j < 8; ++j) A[j] = make_float4(0.f, 0.f, 0.f, 0.f);
  float m = -INFINITY, dsum = 0.f;

  const int woff = (lane & 7) * 32 + (lane >> 3) * 4;  // swizzled stage slot
  float* sEw = &sE[w][0][0];

  for (int n0 = start; n0 < end; n0 += 8) {
    const int nv = end - n0;  // wave-uniform valid row count (>=1)
    #pragma unroll
    for (int r = 0; r < 8; ++r) {
      if (r < nv) {
        const float4 ev = *(const float4*)&E[(size_t)(n0 + r) * 256 + (lane << 2)];
        *(float4*)(sEw + r * 256 + woff) = ev;
      }
    }
    float sc[8];
    #pragma unroll
    for (int r = 0; r < 8; ++r) {
      if (r >= nv) { sc[r] = -INFINITY; continue; }
      const float* er = sEw + r * 256 + dc * 4;
      float a = 0.f;
      #pragma unroll
      for (int j = 0; j < 8; ++j) {
        const float4 ev = *(const float4*)(er + j * 32);
        a += ev.x * rv[j].x + ev.y * rv[j].y + ev.z * rv[j].z + ev.w * rv[j].w;
      }
      a += __shfl_xor(a, 8);
      a += __shfl_xor(a, 16);
      a += __shfl_xor(a, 32);
      sc[r] = a + c0h;
    }
    float bm = sc[0];
    #pragma unroll
    for (int r = 1; r < 8; ++r) bm = fmaxf(bm, sc[r]);
    const float mn = fmaxf(m, bm);
    const float corr = __expf(m - mn);
    float p[8], ps = 0.f;
    #pragma unroll
    for (int r = 0; r < 8; ++r) { p[r] = __expf(sc[r] - mn); ps += p[r]; }
    dsum = dsum * corr + ps;
    m = mn;
    #pragma unroll
    for (int j = 0; j < 8; ++j) {
      A[j].x *= corr; A[j].y *= corr; A[j].z *= corr; A[j].w *= corr;
    }
    #pragma unroll
    for (int r = 0; r < 8; ++r) {
      if (r >= nv) continue;
      const float pr = p[r];
      const float* er = sEw + r * 256 + dc * 4;
      #pragma unroll
      for (int j = 0; j < 8; ++j) {
        const float4 ev = *(const float4*)(er + j * 32);
        A[j].x += pr * ev.x; A[j].y += pr * ev.y;
        A[j].z += pr * ev.z; A[j].w += pr * ev.w;
      }
    }
  }
  const float dinv = (dsum > 0.f) ? 1.f / dsum : 0.f;
  float* ap = &AFws[(size_t)s * 2048 + h * 256 + dc * 32];
  #pragma unroll
  for (int j = 0; j < 8; ++j) {
    float4 a = A[j];
    a.x *= dinv; a.y *= dinv; a.z *= dinv; a.w *= dinv;
    *(float4*)(ap + j * 4) = a;
  }
}

// ---------------------------------------------------------------------------
// K4: pooled[s, h*32+c] = sum_d A_f[s,h,d] * Wv[d, h*32+c] + bv[h*32+c]
// ---------------------------------------------------------------------------
__global__ __launch_bounds__(256) void k4_pooled(
    const float* __restrict__ AFws, const float* __restrict__ Wkv,
    const float* __restrict__ bkv, float* __restrict__ pooled) {
  __shared__ float sWv[256][32];
  const int t = threadIdx.x;
  const int h = blockIdx.x & 7, sg = blockIdx.x >> 3;
  const int s0 = sg * 64;
  #pragma unroll 8
  for (int i = 0; i < 32; ++i) {
    const int id = t + 256 * i;
    sWv[id >> 5][id & 31] = Wkv[(id >> 5) * 512 + 256 + h * 32 + (id & 31)];
  }
  __syncthreads();
  const int c = t & 31, sl = t >> 5;
  const float bv = bkv[256 + h * 32 + c];
  for (int ss = 0; ss < 8; ++ss) {
    const int s = s0 + sl * 8 + ss;
    const float* af = &AFws[(size_t)s * 2048 + h * 256];
    float a = bv;
    #pragma unroll 8
    for (int d4 = 0; d4 < 64; ++d4) {
      const float4 v = *(const float4*)&af[d4 * 4];
      a += v.x * sWv[d4 * 4 + 0][c] + v.y * sWv[d4 * 4 + 1][c]
         + v.z * sWv[d4 * 4 + 2][c] + v.w * sWv[d4 * 4 + 3][c];
    }
    pooled[(size_t)s * 256 + h * 32 + c] = a;
  }
}

// ---------------------------------------------------------------------------
// K5: out = pooled @ Wo + bo, 16 samples per block.
// ---------------------------------------------------------------------------
__global__ __launch_bounds__(256) void k5_out(
    const float* __restrict__ pooled, const float* __restrict__ Wo,
    const float* __restrict__ bo, float* __restrict__ out) {
  __shared__ float sP[16][256];
  const int t = threadIdx.x;
  const int s0 = blockIdx.x * 16;
  #pragma unroll 4
  for (int r = 0; r < 16; ++r) sP[r][t] = pooled[(size_t)(s0 + r) * 256 + t];
  __syncthreads();
  float acc[16];
  const float bot = bo[t];
  #pragma unroll
  for (int r = 0; r < 16; ++r) acc[r] = bot;
  for (int j4 = 0; j4 < 64; ++j4) {
    const float w0 = Wo[(j4 * 4 + 0) * 256 + t];
    const float w1 = Wo[(j4 * 4 + 1) * 256 + t];
    const float w2 = Wo[(j4 * 4 + 2) * 256 + t];
    const float w3 = Wo[(j4 * 4 + 3) * 256 + t];
    #pragma unroll
    for (int r = 0; r < 16; ++r) {
      const float4 pv = *(const float4*)&sP[r][j4 * 4];
      acc[r] += pv.x * w0 + pv.y * w1 + pv.z * w2 + pv.w * w3;
    }
  }
  #pragma unroll
  for (int r = 0; r < 16; ++r) out[(size_t)(s0 + r) * 256 + t] = acc[r];
}

extern "C" void kernel_launch(void* const* d_in, const int* in_sizes, int n_in,
                              void* d_out, int out_size, void* d_ws, size_t ws_size,
                              hipStream_t stream) {
  const float* queries = (const float*)d_in[0];
  const float* E       = (const float*)d_in[1];
  const int*   idx     = (const int*)d_in[2];
  const float* Wq  = (const float*)d_in[4];
  const float* bq  = (const float*)d_in[5];
  const float* Wkv = (const float*)d_in[6];
  const float* bkv = (const float*)d_in[7];
  const float* Wo  = (const float*)d_in[8];
  const float* bo  = (const float*)d_in[9];
  float* out = (float*)d_out;
  const int S = in_sizes[0] / 256;   // 4096
  const int N = in_sizes[1] / 256;   // 262144

  // ws layout: offs[(S+8) ints] | qws[S*256] | Rws[S*2048] | c0[S*8]
  //            | AFws[S*2048] | pooled[S*256]   (~75.6 MB)
  int* offs   = (int*)d_ws;
  float* base = (float*)d_ws + ((S + 8 + 3) & ~3);
  float* qws  = base;
  float* Rws  = qws + (size_t)S * 256;
  float* c0ws = Rws + (size_t)S * 2048;
  float* AFws = c0ws + (size_t)S * 8;
  float* pld  = AFws + (size_t)S * 2048;

  k0_offsets<<<(N + 255) / 256, 256, 0, stream>>>(idx, offs, N, S);
  k2a_q     <<<S / 16,          256, 0, stream>>>(queries, Wq, bq, qws);
  k2b_r     <<<(S / 16) * 8,    256, 0, stream>>>(qws, Wkv, bkv, Rws, c0ws);
  k3_attn   <<<S / 4,           256, 0, stream>>>(E, offs, Rws, c0ws, AFws);
  k4_pooled <<<(S / 64) * 8,    256, 0, stream>>>(AFws, Wkv, bkv, pld);
  k5_out    <<<S / 16,          256, 0, stream>>>(pld, Wo, bo, out);
}